// Round 14
// baseline (53.579 us; speedup 1.0000x reference)
//
#include <hip/hip_runtime.h>
#include <math.h>

#define NROWS 1546
#define INDIM 1546
#define ODIM  64
#define NDRUG 1373
#define MINN  1e-15f
#define MAXNRM 0.996f   // (1 - 4e-3)/sqrt(c), c=1

#define QSTR 256        // packed quad stride: idx = (k>>2)*QSTR + col*4 + (k&3)
#define NQ   387        // ceil(1546/4)
#define NQF  386        // full quads (k < 1544); tail k = 1544,1545
#define NBLK 194        // row-groups of 8
#define NWAV 16         // waves per block (1024 threads)

// constant-address-space scalar loads: compiler MUST emit s_load (read-only assert)
typedef __attribute__((address_space(4))) const float cfloat;
__device__ __forceinline__ cfloat* as4(const float* p) {
    return (cfloat*)(unsigned long long)p;
}

__device__ __forceinline__ float artanh_(float x) {
    x = fminf(fmaxf(x, -1.0f + 1e-7f), 1.0f - 1e-7f);
    return 0.5f * (log1pf(x) - log1pf(-x));
}

__device__ __forceinline__ float wsum(float v) {
#pragma unroll
    for (int off = 32; off > 0; off >>= 1) v += __shfl_xor(v, off, 64);
    return v;
}

// ---- kernel 1: W[64][1546] -> packed Wq (both matrices) ----
__global__ void prep_kernel(const float* __restrict__ Wd, const float* __restrict__ Wm,
                            float* __restrict__ WqD, float* __restrict__ WqM) {
    int total = ODIM * INDIM;
    for (int i = blockIdx.x * blockDim.x + threadIdx.x; i < total; i += gridDim.x * blockDim.x) {
        int o = i / INDIM;
        int k = i - o * INDIM;
        int qi = (k >> 2) * QSTR + o * 4 + (k & 3);
        WqD[qi] = Wd[i];
        WqM[qi] = Wm[i];
    }
}

// ---- kernel 2: full-K x@W^T + hyperbolic epilogue; x via s_load (scalar pipe) ----
__global__ __launch_bounds__(1024) void liner_full(
    const float* __restrict__ X, const float* __restrict__ WqD, const float* __restrict__ WqM,
    const float* __restrict__ bd, const float* __restrict__ bm,
    float* __restrict__ liner, float* __restrict__ xtq) {
    __shared__ float red[NWAV][8][64];
    __shared__ float ssp[2][8];
    __shared__ float hbs[2][64];
    __shared__ float hb2s[2];
    int tid = threadIdx.x, wave = tid >> 6, lane = tid & 63;
    int row0 = blockIdx.x * 8;

    {   // row-norm pass: wave w -> row (w&7), half (w>>3); coalesced vector reads
        int r = wave & 7, half = wave >> 3;
        int gr = min(row0 + r, NROWS - 1);
        int nf2 = half ? 385 : 388;           // 776 + 770 = 1546 floats
        const float2* src = (const float2*)(X + (size_t)gr * INDIM) + half * 388;
        float ss = 0.f;
        for (int c = lane; c < nf2; c += 64) {
            float2 v = src[c];
            ss = fmaf(v.x, v.x, fmaf(v.y, v.y, ss));
        }
        ss = wsum(ss);
        if (lane == 0) ssp[half][r] = ss;
    }

    if (wave < 2) {   // hyp_bias = proj(expmap0(bias)): wave0 drug, wave1 micr
        const float* b = wave ? bm : bd;
        float v = b[lane];
        float un2 = wsum(v * v);
        float un = fmaxf(sqrtf(un2), MINN);
        float e = tanhf(un) * v / un;
        float en2 = wsum(e * e);
        float en = fmaxf(sqrtf(en2), MINN);
        float scl = (en > MAXNRM) ? (MAXNRM / en) : 1.0f;
        hbs[wave][lane] = e * scl;
        if (lane == 0) hb2s[wave] = en2 * scl * scl;
    }

    float acc[8];
#pragma unroll
    for (int r = 0; r < 8; ++r) acc[r] = 0.f;

    // SGPR row bases (clamped rows' results discarded at write)
    cfloat* xrow[8];
#pragma unroll
    for (int r = 0; r < 8; ++r)
        xrow[r] = as4(X + (size_t)min(row0 + r, NROWS - 1) * INDIM);

    int wv = __builtin_amdgcn_readfirstlane(wave);   // uniform wave id
    int qoff = lane * 4;
    bool uni = (row0 + 7 < NDRUG) || (row0 >= NDRUG);
    if (uni) {
        const float* wq = ((row0 < NDRUG) ? WqD : WqM) + qoff;
#pragma unroll 2
        for (int q = wv; q < NQF; q += NWAV) {
            float4 w = *(const float4*)(wq + (size_t)q * QSTR);   // coalesced VMEM
            int k = 4 * q;
#pragma unroll
            for (int r = 0; r < 8; ++r) {                         // s_load x: scalar pipe
                cfloat* xp = xrow[r] + k;
                acc[r] = fmaf(xp[0], w.x, acc[r]);
                acc[r] = fmaf(xp[1], w.y, acc[r]);
                acc[r] = fmaf(xp[2], w.z, acc[r]);
                acc[r] = fmaf(xp[3], w.w, acc[r]);
            }
        }
    } else {
        // single boundary row-group (rows straddle 1373): load both, select per row
        const float* wqd = WqD + qoff;
        const float* wqm = WqM + qoff;
        for (int q = wv; q < NQF; q += NWAV) {
            float4 wd = *(const float4*)(wqd + (size_t)q * QSTR);
            float4 wm = *(const float4*)(wqm + (size_t)q * QSTR);
            int k = 4 * q;
#pragma unroll
            for (int r = 0; r < 8; ++r) {
                bool dd = (row0 + r) < NDRUG;
                float4 w;
                w.x = dd ? wd.x : wm.x; w.y = dd ? wd.y : wm.y;
                w.z = dd ? wd.z : wm.z; w.w = dd ? wd.w : wm.w;
                cfloat* xp = xrow[r] + k;
                acc[r] = fmaf(xp[0], w.x, acc[r]);
                acc[r] = fmaf(xp[1], w.y, acc[r]);
                acc[r] = fmaf(xp[2], w.z, acc[r]);
                acc[r] = fmaf(xp[3], w.w, acc[r]);
            }
        }
    }
    if (wv == 0) {   // scalar K tail: k = 1544,1545
        for (int k = NQF * 4; k < INDIM; ++k) {
            float wdv = WqD[(size_t)(k >> 2) * QSTR + lane * 4 + (k & 3)];
            float wmv = WqM[(size_t)(k >> 2) * QSTR + lane * 4 + (k & 3)];
#pragma unroll
            for (int r = 0; r < 8; ++r) {
                float w = (row0 + r < NDRUG) ? wdv : wmv;
                acc[r] = fmaf(xrow[r][k], w, acc[r]);
            }
        }
    }

#pragma unroll
    for (int r = 0; r < 8; ++r) red[wave][r][lane] = acc[r];
    __syncthreads();

    if (wave < 8) {   // epilogue: one wave per row
        int r = wave;
        int grow = row0 + r;
        if (grow < NROWS) {
            float mx = 0.f;
#pragma unroll
            for (int w = 0; w < NWAV; ++w) mx += red[w][r][lane];
            float xn2 = ssp[0][r] + ssp[1][r];
            float mxn2 = wsum(mx * mx);
            float xn = fmaxf(sqrtf(xn2), MINN);
            float mxn = fmaxf(sqrtf(mxn2), MINN);
            float g = mxn / xn * artanh_(xn);
            float t = tanhf(g);
            float res = t * mx / mxn;          // |res| == |t|
            float rn = fabsf(t);
            if (rn > MAXNRM) { res *= MAXNRM / rn; rn = MAXNRM; }
            int mi = (grow < NDRUG) ? 0 : 1;
            float y = hbs[mi][lane];
            float y2 = hb2s[mi];
            float x2 = rn * rn;
            float xy = wsum(res * y);
            float num = (1.0f + 2.0f * xy + y2) * res + (1.0f - x2) * y;
            float den = 1.0f + 2.0f * xy + x2 * y2;
            float v = num / fmaxf(den, MINN);
            float v2 = wsum(v * v);
            float vn = fmaxf(sqrtf(v2), MINN);
            if (vn > MAXNRM) { v *= MAXNRM / vn; vn = MAXNRM; }
            float xt = artanh_(vn) / vn * v;   // logmap0
            liner[(size_t)grow * ODIM + lane] = v;
            xtq[(size_t)(grow >> 2) * QSTR + lane * 4 + (grow & 3)] = xt;
        }
    }
}

// ---- kernel 3: full-K adj@xtan + HypAct; adj via s_load; fused adj copy ----
__global__ __launch_bounds__(1024) void agg_full(
    const float* __restrict__ ADJ, const float* __restrict__ xtq,
    const float* __restrict__ liner, const float* __restrict__ WN /*[128][64]*/,
    const float* __restrict__ biasnode, float* __restrict__ out_h,
    float* __restrict__ adj_out) {
    __shared__ float red[NWAV][8][64];
    __shared__ float zl[8][128];
    int tid = threadIdx.x, wave = tid >> 6, lane = tid & 63;
    int row0 = blockIdx.x * 8;

    {   // adj copy pass (global->global, coalesced; no barrier needed)
        int r = wave & 7, half = wave >> 3;
        int gr0 = row0 + r;
        if (gr0 < NROWS) {
            int nf2 = half ? 385 : 388;
            const float2* src = (const float2*)(ADJ + (size_t)gr0 * INDIM) + half * 388;
            float2* cp = (float2*)(adj_out + (size_t)gr0 * INDIM) + half * 388;
            for (int c = lane; c < nf2; c += 64) cp[c] = src[c];
        }
    }

    float acc[8];
#pragma unroll
    for (int r = 0; r < 8; ++r) acc[r] = 0.f;

    cfloat* arow[8];
#pragma unroll
    for (int r = 0; r < 8; ++r)
        arow[r] = as4(ADJ + (size_t)min(row0 + r, NROWS - 1) * INDIM);

    int wv = __builtin_amdgcn_readfirstlane(wave);
    const float* wq = xtq + lane * 4;
#pragma unroll 2
    for (int q = wv; q < NQF; q += NWAV) {
        float4 w = *(const float4*)(wq + (size_t)q * QSTR);
        int k = 4 * q;
#pragma unroll
        for (int r = 0; r < 8; ++r) {
            cfloat* xp = arow[r] + k;
            acc[r] = fmaf(xp[0], w.x, acc[r]);
            acc[r] = fmaf(xp[1], w.y, acc[r]);
            acc[r] = fmaf(xp[2], w.z, acc[r]);
            acc[r] = fmaf(xp[3], w.w, acc[r]);
        }
    }
    if (wv == 0) {   // scalar K tail: k = 1544,1545
        for (int k = NQF * 4; k < INDIM; ++k) {
            float w = xtq[(size_t)(k >> 2) * QSTR + lane * 4 + (k & 3)];
#pragma unroll
            for (int r = 0; r < 8; ++r) acc[r] = fmaf(arow[r][k], w, acc[r]);
        }
    }

#pragma unroll
    for (int r = 0; r < 8; ++r) red[wave][r][lane] = acc[r];
    __syncthreads();

    if (wave < 8) {   // epilogue: one wave per row (HypAct)
        int r = wave;
        int grow = row0 + r;
        if (grow < NROWS) {
            float s = 0.f;
#pragma unroll
            for (int w = 0; w < NWAV; ++w) s += red[w][r][lane];
            float sn2 = wsum(s * s);
            float sn = fmaxf(sqrtf(sn2), MINN);
            float th = tanhf(sn);
            float agg = th * s / sn;           // expmap0; |agg| == th
            if (th > MAXNRM) agg *= MAXNRM / th;
            float lin = liner[(size_t)grow * ODIM + lane];
            zl[r][lane] = agg;
            zl[r][64 + lane] = lin;            // same-wave LDS RAW, no barrier needed
            float d = biasnode[grow];
            const float* w = WN + lane;
#pragma unroll 8
            for (int f = 0; f < 128; ++f) d = fmaf(zl[r][f], w[f * 64], d);
            d = fmaxf(d, 0.0f);
            out_h[(size_t)grow * ODIM + lane] = d * agg + (1.0f - d) * lin;
        }
    }
}

extern "C" void kernel_launch(void* const* d_in, const int* in_sizes, int n_in,
                              void* d_out, int out_size, void* d_ws, size_t ws_size,
                              hipStream_t stream) {
    const float* x   = (const float*)d_in[0];
    const float* adj = (const float*)d_in[1];
    const float* Wd  = (const float*)d_in[2];
    const float* Wm  = (const float*)d_in[3];
    const float* bd  = (const float*)d_in[4];
    const float* bm  = (const float*)d_in[5];
    const float* wn  = (const float*)d_in[6];
    const float* bn  = (const float*)d_in[7];
    float* out = (float*)d_out;
    float* ws  = (float*)d_ws;

    const int WELEMS = ODIM * INDIM;          // 98944
    const int QELEMS = NQ * QSTR;             // 99072
    float* WqD   = ws;                        // 99072
    float* WqM   = WqD + QELEMS;              // 99072
    float* liner = WqM + QELEMS;              // 98944
    float* xtq   = liner + WELEMS;            // 99072 (packed)

    prep_kernel<<<256, 256, 0, stream>>>(Wd, Wm, WqD, WqM);
    liner_full<<<NBLK, 1024, 0, stream>>>(x, WqD, WqM, bd, bm, liner, xtq);
    agg_full<<<NBLK, 1024, 0, stream>>>(adj, xtq, liner, wn, bn, out,
                                        out + WELEMS);
}

// Round 15
// 35.850 us; speedup vs baseline: 1.4945x; 1.4945x over previous
//
#include <hip/hip_runtime.h>
#include <math.h>

#define NROWS 1546
#define INDIM 1546
#define ODIM  64
#define NDRUG 1373
#define MINN  1e-15f
#define MAXNRM 0.996f   // (1 - 4e-3)/sqrt(c), c=1

#define KS     4                     // k-chunks = waves per gemm block
#define KSTEPS 49                    // ceil(1546/32); step 48 is the masked tail
#define FRAGSZ (KSTEPS * 4 * 512)    // bf16 elems per packed B matrix = 100352

typedef short  short8 __attribute__((ext_vector_type(8)));
typedef float  f32x4  __attribute__((ext_vector_type(4)));

__device__ __forceinline__ unsigned short f2bf(float f) {   // RNE f32->bf16
    unsigned u = __float_as_uint(f);
    u += 0x7FFFu + ((u >> 16) & 1u);
    return (unsigned short)(u >> 16);
}

__device__ __forceinline__ float artanh_(float x) {
    x = fminf(fmaxf(x, -1.0f + 1e-7f), 1.0f - 1e-7f);
    return 0.5f * (log1pf(x) - log1pf(-x));
}

__device__ __forceinline__ float wsum(float v) {
#pragma unroll
    for (int off = 32; off > 0; off >>= 1) v += __shfl_xor(v, off, 64);
    return v;
}

// ---- kernel 1: W -> bf16 B-frags (blocks 0-63), bias (64), adj copy (65+) ----
__global__ void prep_kernel(const float* __restrict__ Wd, const float* __restrict__ Wm,
                            unsigned short* __restrict__ WfD, unsigned short* __restrict__ WfM,
                            const float* __restrict__ bd, const float* __restrict__ bm,
                            float* __restrict__ hbD, float* __restrict__ hbM,
                            float* __restrict__ hb2,
                            const float4* __restrict__ adj4, float4* __restrict__ adjout4,
                            int n4) {
    int tid = threadIdx.x;
    if (blockIdx.x < 64) {
        // B[k][col=o] = W[o][k]; frag elem: lane=( (k&31)>>3 )*16 + (o&15), j=k&7
        int total = 64 * 1568;     // 100352 per matrix
        for (int i = blockIdx.x * 256 + tid; i < total; i += 64 * 256) {
            int o = i / 1568, k = i - o * 1568;
            int kstep = k >> 5, rem = k & 31, lgrp = rem >> 3, j = rem & 7;
            int addr = (kstep * 4 + (o >> 4)) * 512 + (lgrp * 16 + (o & 15)) * 8 + j;
            float vd = (k < INDIM) ? Wd[o * INDIM + k] : 0.f;
            float vm = (k < INDIM) ? Wm[o * INDIM + k] : 0.f;
            WfD[addr] = f2bf(vd);
            WfM[addr] = f2bf(vm);
        }
        return;
    }
    if (blockIdx.x == 64) {
        if (tid < 128) {
            int wave = tid >> 6, lane = tid & 63;
            const float* b = wave ? bm : bd;
            float v = b[lane];
            float un2 = wsum(v * v);
            float un = fmaxf(sqrtf(un2), MINN);
            float e = tanhf(un) * v / un;
            float en2 = wsum(e * e);
            float en = fmaxf(sqrtf(en2), MINN);
            float scl = (en > MAXNRM) ? (MAXNRM / en) : 1.0f;
            float* hb = wave ? hbM : hbD;
            hb[lane] = e * scl;
            if (lane == 0) hb2[wave] = en2 * scl * scl;
        }
        return;
    }
    int nb = gridDim.x - 65;
    for (int i = (blockIdx.x - 65) * 256 + tid; i < n4; i += nb * 256)
        adjout4[i] = adj4[i];
}

// ---- kernel 2: x@W^T via bf16 MFMA; 16-row strip/block, 4 waves = 4 k-chunks ----
__global__ __launch_bounds__(256) void gemm_liner_mfma(
    const float* __restrict__ X,
    const unsigned short* __restrict__ WfD, const unsigned short* __restrict__ WfM,
    float* __restrict__ part, float* __restrict__ pnorm) {
    int s = blockIdx.x;                       // 0..97; 97 = strip 85 redo with Wm
    int strip = (s == 97) ? 85 : s;
    int rowbase = strip * 16;
    int kc = threadIdx.x >> 6, lane = threadIdx.x & 63;
    int lrow = lane & 15, lgrp = lane >> 4;
    const unsigned short* Bf = (s <= 85) ? WfD : WfM;
    int lo = (s == 97) ? NDRUG : 0;
    int hi = (s == 85) ? NDRUG : NROWS;
    const float* arow = X + (size_t)min(rowbase + lrow, NROWS - 1) * INDIM;

    f32x4 ac0 = {0,0,0,0}, ac1 = {0,0,0,0}, ac2 = {0,0,0,0}, ac3 = {0,0,0,0};
    float ss = 0.f;
    int ks0 = 12 * kc;
    int ks1 = 12 * kc + 12;                   // kc==3: 36..47 + tail below
    for (int ks = ks0; ks < ks1; ++ks) {
        const float* xp = arow + ks * 32 + lgrp * 8;
        float2 p0 = *(const float2*)(xp);
        float2 p1 = *(const float2*)(xp + 2);
        float2 p2 = *(const float2*)(xp + 4);
        float2 p3 = *(const float2*)(xp + 6);
        float xv[8] = {p0.x, p0.y, p1.x, p1.y, p2.x, p2.y, p3.x, p3.y};
        short8 av;
#pragma unroll
        for (int j = 0; j < 8; ++j) { ss = fmaf(xv[j], xv[j], ss); av[j] = (short)f2bf(xv[j]); }
        const unsigned short* bp = Bf + (size_t)(ks * 4) * 512 + lane * 8;
        short8 b0 = *(const short8*)(bp);
        short8 b1 = *(const short8*)(bp + 512);
        short8 b2 = *(const short8*)(bp + 1024);
        short8 b3 = *(const short8*)(bp + 1536);
        ac0 = __builtin_amdgcn_mfma_f32_16x16x32_bf16(av, b0, ac0, 0, 0, 0);
        ac1 = __builtin_amdgcn_mfma_f32_16x16x32_bf16(av, b1, ac1, 0, 0, 0);
        ac2 = __builtin_amdgcn_mfma_f32_16x16x32_bf16(av, b2, ac2, 0, 0, 0);
        ac3 = __builtin_amdgcn_mfma_f32_16x16x32_bf16(av, b3, ac3, 0, 0, 0);
    }
    if (kc == 3) {                            // tail kstep 48: k = 1536..1567 masked
        short8 av;
#pragma unroll
        for (int j = 0; j < 8; ++j) {
            int k = 1536 + lgrp * 8 + j;
            float v = (k < INDIM) ? arow[k] : 0.f;
            ss = fmaf(v, v, ss);
            av[j] = (short)f2bf(v);
        }
        const unsigned short* bp = Bf + (size_t)(48 * 4) * 512 + lane * 8;
        short8 b0 = *(const short8*)(bp);
        short8 b1 = *(const short8*)(bp + 512);
        short8 b2 = *(const short8*)(bp + 1024);
        short8 b3 = *(const short8*)(bp + 1536);
        ac0 = __builtin_amdgcn_mfma_f32_16x16x32_bf16(av, b0, ac0, 0, 0, 0);
        ac1 = __builtin_amdgcn_mfma_f32_16x16x32_bf16(av, b1, ac1, 0, 0, 0);
        ac2 = __builtin_amdgcn_mfma_f32_16x16x32_bf16(av, b2, ac2, 0, 0, 0);
        ac3 = __builtin_amdgcn_mfma_f32_16x16x32_bf16(av, b3, ac3, 0, 0, 0);
    }
    // pnorm: sum the 4 lane-groups sharing a row (f32-accurate)
    ss += __shfl_xor(ss, 16, 64);
    ss += __shfl_xor(ss, 32, 64);
    if (s != 97 && lane < 16) {
        int r = rowbase + lrow;
        if (r < NROWS) pnorm[r * KS + kc] = ss;
    }
    // C store: row = rowbase + lgrp*4 + i, col = t*16 + lrow (verified C/D layout)
#pragma unroll
    for (int i = 0; i < 4; ++i) {
        int r = rowbase + lgrp * 4 + i;
        if (r >= lo && r < hi) {
            size_t base = (size_t)r * (KS * 64) + kc * 64 + lrow;
            part[base]      = ac0[i];
            part[base + 16] = ac1[i];
            part[base + 32] = ac2[i];
            part[base + 48] = ac3[i];
        }
    }
}

// ---- kernel 3: reduce partials + hyperbolic epilogue -> liner (f32), xtf (bf16 frags) ----
__global__ __launch_bounds__(512) void linerB(
    const float* __restrict__ part, const float* __restrict__ pnorm,
    const float* __restrict__ hbD, const float* __restrict__ hbM, const float* __restrict__ hb2v,
    float* __restrict__ liner, unsigned short* __restrict__ xtf) {
    int wave = threadIdx.x >> 6, lane = threadIdx.x & 63;
    int grow = blockIdx.x * 8 + wave;
    if (grow >= NROWS) {                      // block 193 waves 2-7: zero-pad rows 1546..1567
        for (int row = grow; row < 1568; row += 6)
            xtf[((row >> 5) * 4 + (lane >> 4)) * 512 +
                (((row & 31) >> 3) * 16 + (lane & 15)) * 8 + (row & 7)] = 0;
        return;
    }
    float mx = 0.f, xn2 = 0.f;
#pragma unroll
    for (int kc = 0; kc < KS; ++kc) mx += part[(size_t)grow * (KS * 64) + kc * 64 + lane];
#pragma unroll
    for (int kc = 0; kc < KS; ++kc) xn2 += pnorm[grow * KS + kc];

    float mxn2 = wsum(mx * mx);
    float xn = fmaxf(sqrtf(xn2), MINN);
    float mxn = fmaxf(sqrtf(mxn2), MINN);
    float g = mxn / xn * artanh_(xn);
    float t = tanhf(g);
    float res = t * mx / mxn;                 // |res| == |t|
    float rn = fabsf(t);
    if (rn > MAXNRM) { res *= MAXNRM / rn; rn = MAXNRM; }
    const float* hb = (grow < NDRUG) ? hbD : hbM;
    float y = hb[lane];
    float y2 = hb2v[(grow < NDRUG) ? 0 : 1];
    float x2 = rn * rn;
    float xy = wsum(res * y);
    float num = (1.0f + 2.0f * xy + y2) * res + (1.0f - x2) * y;
    float den = 1.0f + 2.0f * xy + x2 * y2;
    float v = num / fmaxf(den, MINN);
    float v2 = wsum(v * v);
    float vn = fmaxf(sqrtf(v2), MINN);
    if (vn > MAXNRM) { v *= MAXNRM / vn; vn = MAXNRM; }
    float xt = artanh_(vn) / vn * v;          // logmap0
    liner[(size_t)grow * ODIM + lane] = v;
    // write xt as bf16 into B-frag layout: element (k=grow, col=lane)
    xtf[((grow >> 5) * 4 + (lane >> 4)) * 512 +
        (((grow & 31) >> 3) * 16 + (lane & 15)) * 8 + (grow & 7)] = f2bf(xt);
}

// ---- kernel 4: adj@xtan via bf16 MFMA ----
__global__ __launch_bounds__(256) void gemm_agg_mfma(
    const float* __restrict__ ADJ, const unsigned short* __restrict__ xtf,
    float* __restrict__ part) {
    int rowbase = blockIdx.x * 16;            // 97 blocks
    int kc = threadIdx.x >> 6, lane = threadIdx.x & 63;
    int lrow = lane & 15, lgrp = lane >> 4;
    const float* arow = ADJ + (size_t)min(rowbase + lrow, NROWS - 1) * INDIM;

    f32x4 ac0 = {0,0,0,0}, ac1 = {0,0,0,0}, ac2 = {0,0,0,0}, ac3 = {0,0,0,0};
    int ks0 = 12 * kc;
    int ks1 = 12 * kc + 12;
    for (int ks = ks0; ks < ks1; ++ks) {
        const float* xp = arow + ks * 32 + lgrp * 8;
        float2 p0 = *(const float2*)(xp);
        float2 p1 = *(const float2*)(xp + 2);
        float2 p2 = *(const float2*)(xp + 4);
        float2 p3 = *(const float2*)(xp + 6);
        float xv[8] = {p0.x, p0.y, p1.x, p1.y, p2.x, p2.y, p3.x, p3.y};
        short8 av;
#pragma unroll
        for (int j = 0; j < 8; ++j) av[j] = (short)f2bf(xv[j]);
        const unsigned short* bp = xtf + (size_t)(ks * 4) * 512 + lane * 8;
        short8 b0 = *(const short8*)(bp);
        short8 b1 = *(const short8*)(bp + 512);
        short8 b2 = *(const short8*)(bp + 1024);
        short8 b3 = *(const short8*)(bp + 1536);
        ac0 = __builtin_amdgcn_mfma_f32_16x16x32_bf16(av, b0, ac0, 0, 0, 0);
        ac1 = __builtin_amdgcn_mfma_f32_16x16x32_bf16(av, b1, ac1, 0, 0, 0);
        ac2 = __builtin_amdgcn_mfma_f32_16x16x32_bf16(av, b2, ac2, 0, 0, 0);
        ac3 = __builtin_amdgcn_mfma_f32_16x16x32_bf16(av, b3, ac3, 0, 0, 0);
    }
    if (kc == 3) {                            // masked tail kstep 48
        short8 av;
#pragma unroll
        for (int j = 0; j < 8; ++j) {
            int k = 1536 + lgrp * 8 + j;
            av[j] = (short)f2bf((k < INDIM) ? arow[k] : 0.f);
        }
        const unsigned short* bp = xtf + (size_t)(48 * 4) * 512 + lane * 8;
        short8 b0 = *(const short8*)(bp);
        short8 b1 = *(const short8*)(bp + 512);
        short8 b2 = *(const short8*)(bp + 1024);
        short8 b3 = *(const short8*)(bp + 1536);
        ac0 = __builtin_amdgcn_mfma_f32_16x16x32_bf16(av, b0, ac0, 0, 0, 0);
        ac1 = __builtin_amdgcn_mfma_f32_16x16x32_bf16(av, b1, ac1, 0, 0, 0);
        ac2 = __builtin_amdgcn_mfma_f32_16x16x32_bf16(av, b2, ac2, 0, 0, 0);
        ac3 = __builtin_amdgcn_mfma_f32_16x16x32_bf16(av, b3, ac3, 0, 0, 0);
    }
#pragma unroll
    for (int i = 0; i < 4; ++i) {
        int r = rowbase + lgrp * 4 + i;
        if (r < NROWS) {
            size_t base = (size_t)r * (KS * 64) + kc * 64 + lrow;
            part[base]      = ac0[i];
            part[base + 16] = ac1[i];
            part[base + 32] = ac2[i];
            part[base + 48] = ac3[i];
        }
    }
}

// ---- kernel 5: reduce partials + expmap0/proj + gated HypAct -> h ----
__global__ __launch_bounds__(512) void aggB(
    const float* __restrict__ part, const float* __restrict__ liner,
    const float* __restrict__ WN /*[128][64]*/, const float* __restrict__ biasnode,
    float* __restrict__ out_h) {
    __shared__ float zl[8][128];
    int wave = threadIdx.x >> 6, lane = threadIdx.x & 63;
    int grow = blockIdx.x * 8 + wave;
    if (grow >= NROWS) return;
    float s = 0.f;
#pragma unroll
    for (int kc = 0; kc < KS; ++kc) s += part[(size_t)grow * (KS * 64) + kc * 64 + lane];
    float sn2 = wsum(s * s);
    float sn = fmaxf(sqrtf(sn2), MINN);
    float th = tanhf(sn);
    float agg = th * s / sn;                  // expmap0; |agg| == th
    if (th > MAXNRM) agg *= MAXNRM / th;
    float lin = liner[(size_t)grow * ODIM + lane];
    zl[wave][lane] = agg;
    zl[wave][64 + lane] = lin;                // same-wave LDS RAW, no barrier needed
    float d = biasnode[grow];
    const float* w = WN + lane;
#pragma unroll 8
    for (int f = 0; f < 128; ++f) d = fmaf(zl[wave][f], w[f * 64], d);
    d = fmaxf(d, 0.0f);
    out_h[(size_t)grow * ODIM + lane] = d * agg + (1.0f - d) * lin;
}

extern "C" void kernel_launch(void* const* d_in, const int* in_sizes, int n_in,
                              void* d_out, int out_size, void* d_ws, size_t ws_size,
                              hipStream_t stream) {
    const float* x   = (const float*)d_in[0];
    const float* adj = (const float*)d_in[1];
    const float* Wd  = (const float*)d_in[2];
    const float* Wm  = (const float*)d_in[3];
    const float* bd  = (const float*)d_in[4];
    const float* bm  = (const float*)d_in[5];
    const float* wn  = (const float*)d_in[6];
    const float* bn  = (const float*)d_in[7];
    float* out = (float*)d_out;

    const int WELEMS = ODIM * INDIM;              // 98944
    unsigned short* WfD = (unsigned short*)d_ws;  // 100352 ushorts
    unsigned short* WfM = WfD + FRAGSZ;
    unsigned short* xtf = WfM + FRAGSZ;
    float* hbD   = (float*)(xtf + FRAGSZ);        // 3*200704 B = 4B-aligned
    float* hbM   = hbD + 64;
    float* hb2   = hbM + 64;
    float* liner = hbD + 192;                     // 98944
    float* pnorm = liner + WELEMS;                // 1546*4
    float* part  = pnorm + 6184;                  // 1546*4*64 = 395776

    int n4 = (NROWS * NROWS) / 4;                 // 597529
    prep_kernel<<<512, 256, 0, stream>>>(Wd, Wm, WfD, WfM, bd, bm, hbD, hbM, hb2,
                                         (const float4*)adj, (float4*)(out + WELEMS), n4);
    gemm_liner_mfma<<<98, 256, 0, stream>>>(x, WfD, WfM, part, pnorm);
    linerB<<<194, 512, 0, stream>>>(part, pnorm, hbD, hbM, hb2, liner, xtf);
    gemm_agg_mfma<<<97, 256, 0, stream>>>(adj, xtf, part);
    aggB<<<194, 512, 0, stream>>>(part, liner, wn, bn, out);
}

// Round 16
// 35.593 us; speedup vs baseline: 1.5053x; 1.0072x over previous
//
#include <hip/hip_runtime.h>
#include <math.h>

#define NROWS 1546
#define INDIM 1546
#define ODIM  64
#define NDRUG 1373
#define MINN  1e-15f
#define MAXNRM 0.996f   // (1 - 4e-3)/sqrt(c), c=1

#define KSTEPS 49                    // ceil(1546/32); step 48 is the masked tail
#define FRAGSZ (KSTEPS * 4 * 512)    // bf16 elems per packed B matrix = 100352
#define REDS   65                    // padded LDS reduce stride

typedef short  short8 __attribute__((ext_vector_type(8)));
typedef float  f32x4  __attribute__((ext_vector_type(4)));

__device__ __forceinline__ unsigned short f2bf(float f) {   // RNE f32->bf16
    unsigned u = __float_as_uint(f);
    u += 0x7FFFu + ((u >> 16) & 1u);
    return (unsigned short)(u >> 16);
}

__device__ __forceinline__ int fragaddr(int k, int col) {   // B-frag element addr
    return ((k >> 5) * 4 + (col >> 4)) * 512 + (((k & 31) >> 3) * 16 + (col & 15)) * 8 + (k & 7);
}

__device__ __forceinline__ float artanh_(float x) {
    x = fminf(fmaxf(x, -1.0f + 1e-7f), 1.0f - 1e-7f);
    return 0.5f * (log1pf(x) - log1pf(-x));
}

__device__ __forceinline__ float wsum(float v) {
#pragma unroll
    for (int off = 32; off > 0; off >>= 1) v += __shfl_xor(v, off, 64);
    return v;
}

// ---- kernel 1: W -> bf16 B-frags (blocks 0-63), bias (64), adj copy (65+) ----
__global__ void prep_kernel(const float* __restrict__ Wd, const float* __restrict__ Wm,
                            unsigned short* __restrict__ WfD, unsigned short* __restrict__ WfM,
                            const float* __restrict__ bd, const float* __restrict__ bm,
                            float* __restrict__ hbD, float* __restrict__ hbM,
                            float* __restrict__ hb2,
                            const float4* __restrict__ adj4, float4* __restrict__ adjout4,
                            int n4) {
    int tid = threadIdx.x;
    if (blockIdx.x < 64) {
        int total = 64 * 1568;     // 100352 per matrix
        for (int i = blockIdx.x * 256 + tid; i < total; i += 64 * 256) {
            int o = i / 1568, k = i - o * 1568;
            int addr = fragaddr(k, o);
            float vd = (k < INDIM) ? Wd[o * INDIM + k] : 0.f;
            float vm = (k < INDIM) ? Wm[o * INDIM + k] : 0.f;
            WfD[addr] = f2bf(vd);
            WfM[addr] = f2bf(vm);
        }
        return;
    }
    if (blockIdx.x == 64) {
        if (tid < 128) {
            int wave = tid >> 6, lane = tid & 63;
            const float* b = wave ? bm : bd;
            float v = b[lane];
            float un2 = wsum(v * v);
            float un = fmaxf(sqrtf(un2), MINN);
            float e = tanhf(un) * v / un;
            float en2 = wsum(e * e);
            float en = fmaxf(sqrtf(en2), MINN);
            float scl = (en > MAXNRM) ? (MAXNRM / en) : 1.0f;
            float* hb = wave ? hbM : hbD;
            hb[lane] = e * scl;
            if (lane == 0) hb2[wave] = en2 * scl * scl;
        }
        return;
    }
    int nb = gridDim.x - 65;
    for (int i = (blockIdx.x - 65) * 256 + tid; i < n4; i += nb * 256)
        adjout4[i] = adj4[i];
}

// ---- kernel 2: x@W^T MFMA + in-block reduce + hyperbolic epilogue ----
__global__ __launch_bounds__(512) void liner_fused(
    const float* __restrict__ X,
    const unsigned short* __restrict__ WfD, const unsigned short* __restrict__ WfM,
    const float* __restrict__ hbD, const float* __restrict__ hbM, const float* __restrict__ hb2v,
    float* __restrict__ liner, unsigned short* __restrict__ xtf) {
    __shared__ float red[8][16][REDS];     // 33.3 KB
    __shared__ float ssl[8][16];
    int tid = threadIdx.x, kc = tid >> 6, lane = tid & 63;
    int lrow = lane & 15, lgrp = lane >> 4;
    int s = blockIdx.x;                    // 0..97; 97 = strip 85 redo with Wm
    int strip = (s == 97) ? 85 : s;
    int rowbase = strip * 16;
    const unsigned short* Bf = (s <= 85) ? WfD : WfM;
    int lo = (s == 97) ? NDRUG : 0;
    int hi = (s == 85) ? NDRUG : NROWS;
    const float* arow = X + (size_t)min(rowbase + lrow, NROWS - 1) * INDIM;

    f32x4 ac0 = {0,0,0,0}, ac1 = {0,0,0,0}, ac2 = {0,0,0,0}, ac3 = {0,0,0,0};
    float ss = 0.f;
    for (int ks = kc; ks < 48; ks += 8) {  // 6 full k-steps per wave
        const float* xp = arow + ks * 32 + lgrp * 8;
        float2 p0 = *(const float2*)(xp);
        float2 p1 = *(const float2*)(xp + 2);
        float2 p2 = *(const float2*)(xp + 4);
        float2 p3 = *(const float2*)(xp + 6);
        float xv[8] = {p0.x, p0.y, p1.x, p1.y, p2.x, p2.y, p3.x, p3.y};
        short8 av;
#pragma unroll
        for (int j = 0; j < 8; ++j) { ss = fmaf(xv[j], xv[j], ss); av[j] = (short)f2bf(xv[j]); }
        const unsigned short* bp = Bf + (size_t)(ks * 4) * 512 + lane * 8;
        short8 b0 = *(const short8*)(bp);
        short8 b1 = *(const short8*)(bp + 512);
        short8 b2 = *(const short8*)(bp + 1024);
        short8 b3 = *(const short8*)(bp + 1536);
        ac0 = __builtin_amdgcn_mfma_f32_16x16x32_bf16(av, b0, ac0, 0, 0, 0);
        ac1 = __builtin_amdgcn_mfma_f32_16x16x32_bf16(av, b1, ac1, 0, 0, 0);
        ac2 = __builtin_amdgcn_mfma_f32_16x16x32_bf16(av, b2, ac2, 0, 0, 0);
        ac3 = __builtin_amdgcn_mfma_f32_16x16x32_bf16(av, b3, ac3, 0, 0, 0);
    }
    if (kc == 0) {                         // masked tail kstep 48 (k = 1536..1567)
        short8 av;
#pragma unroll
        for (int j = 0; j < 8; ++j) {
            int k = 1536 + lgrp * 8 + j;
            float v = (k < INDIM) ? arow[k] : 0.f;
            ss = fmaf(v, v, ss);
            av[j] = (short)f2bf(v);
        }
        const unsigned short* bp = Bf + (size_t)(48 * 4) * 512 + lane * 8;
        short8 b0 = *(const short8*)(bp);
        short8 b1 = *(const short8*)(bp + 512);
        short8 b2 = *(const short8*)(bp + 1024);
        short8 b3 = *(const short8*)(bp + 1536);
        ac0 = __builtin_amdgcn_mfma_f32_16x16x32_bf16(av, b0, ac0, 0, 0, 0);
        ac1 = __builtin_amdgcn_mfma_f32_16x16x32_bf16(av, b1, ac1, 0, 0, 0);
        ac2 = __builtin_amdgcn_mfma_f32_16x16x32_bf16(av, b2, ac2, 0, 0, 0);
        ac3 = __builtin_amdgcn_mfma_f32_16x16x32_bf16(av, b3, ac3, 0, 0, 0);
    }
    // per-row Σx² within this wave's k-subset
    ss += __shfl_xor(ss, 16, 64);
    ss += __shfl_xor(ss, 32, 64);
    if (lane < 16) ssl[kc][lrow] = ss;
    // partials -> LDS (C/D layout: row=lgrp*4+i, col=t*16+lrow)
#pragma unroll
    for (int i = 0; i < 4; ++i) {
        int r = lgrp * 4 + i;
        red[kc][r][lrow]      = ac0[i];
        red[kc][r][16 + lrow] = ac1[i];
        red[kc][r][32 + lrow] = ac2[i];
        red[kc][r][48 + lrow] = ac3[i];
    }
    __syncthreads();

    // epilogue: wave kc handles rows 2kc, 2kc+1
#pragma unroll
    for (int j = 0; j < 2; ++j) {
        int r = 2 * kc + j;
        int grow = rowbase + r;
        if (grow >= lo && grow < hi) {     // wave-uniform guard
            float mx = 0.f, xn2 = 0.f;
#pragma unroll
            for (int w = 0; w < 8; ++w) { mx += red[w][r][lane]; xn2 += ssl[w][r]; }
            float mxn2 = wsum(mx * mx);
            float xn = fmaxf(sqrtf(xn2), MINN);
            float mxn = fmaxf(sqrtf(mxn2), MINN);
            float g = mxn / xn * artanh_(xn);
            float t = tanhf(g);
            float res = t * mx / mxn;      // |res| == |t|
            float rn = fabsf(t);
            if (rn > MAXNRM) { res *= MAXNRM / rn; rn = MAXNRM; }
            const float* hb = (grow < NDRUG) ? hbD : hbM;
            float y = hb[lane];
            float y2 = hb2v[(grow < NDRUG) ? 0 : 1];
            float x2 = rn * rn;
            float xy = wsum(res * y);
            float num = (1.0f + 2.0f * xy + y2) * res + (1.0f - x2) * y;
            float den = 1.0f + 2.0f * xy + x2 * y2;
            float v = num / fmaxf(den, MINN);
            float v2 = wsum(v * v);
            float vn = fmaxf(sqrtf(v2), MINN);
            if (vn > MAXNRM) { v *= MAXNRM / vn; vn = MAXNRM; }
            float xt = artanh_(vn) / vn * v;   // logmap0
            liner[(size_t)grow * ODIM + lane] = v;
            xtf[fragaddr(grow, lane)] = f2bf(xt);
        }
    }
    if (s == 96) {                         // zero-pad xtf rows 1546..1567
        for (int row = NROWS + kc; row < 1568; row += 8)
            xtf[fragaddr(row, lane)] = 0;
    }
}

// ---- kernel 3: adj@xtan MFMA + in-block reduce + gated HypAct -> h ----
__global__ __launch_bounds__(512) void agg_fused(
    const float* __restrict__ ADJ, const unsigned short* __restrict__ xtf,
    const float* __restrict__ liner, const float* __restrict__ WN /*[128][64]*/,
    const float* __restrict__ biasnode, float* __restrict__ out_h) {
    __shared__ float red[8][16][REDS];     // 33.3 KB
    __shared__ float zl[16][128];          // 8 KB
    int tid = threadIdx.x, kc = tid >> 6, lane = tid & 63;
    int lrow = lane & 15, lgrp = lane >> 4;
    int rowbase = blockIdx.x * 16;         // 97 blocks
    const float* arow = ADJ + (size_t)min(rowbase + lrow, NROWS - 1) * INDIM;

    f32x4 ac0 = {0,0,0,0}, ac1 = {0,0,0,0}, ac2 = {0,0,0,0}, ac3 = {0,0,0,0};
    for (int ks = kc; ks < 48; ks += 8) {
        const float* xp = arow + ks * 32 + lgrp * 8;
        float2 p0 = *(const float2*)(xp);
        float2 p1 = *(const float2*)(xp + 2);
        float2 p2 = *(const float2*)(xp + 4);
        float2 p3 = *(const float2*)(xp + 6);
        float xv[8] = {p0.x, p0.y, p1.x, p1.y, p2.x, p2.y, p3.x, p3.y};
        short8 av;
#pragma unroll
        for (int j = 0; j < 8; ++j) av[j] = (short)f2bf(xv[j]);
        const unsigned short* bp = xtf + (size_t)(ks * 4) * 512 + lane * 8;
        short8 b0 = *(const short8*)(bp);
        short8 b1 = *(const short8*)(bp + 512);
        short8 b2 = *(const short8*)(bp + 1024);
        short8 b3 = *(const short8*)(bp + 1536);
        ac0 = __builtin_amdgcn_mfma_f32_16x16x32_bf16(av, b0, ac0, 0, 0, 0);
        ac1 = __builtin_amdgcn_mfma_f32_16x16x32_bf16(av, b1, ac1, 0, 0, 0);
        ac2 = __builtin_amdgcn_mfma_f32_16x16x32_bf16(av, b2, ac2, 0, 0, 0);
        ac3 = __builtin_amdgcn_mfma_f32_16x16x32_bf16(av, b3, ac3, 0, 0, 0);
    }
    if (kc == 0) {                         // masked tail kstep 48
        short8 av;
#pragma unroll
        for (int j = 0; j < 8; ++j) {
            int k = 1536 + lgrp * 8 + j;
            av[j] = (short)f2bf((k < INDIM) ? arow[k] : 0.f);
        }
        const unsigned short* bp = xtf + (size_t)(48 * 4) * 512 + lane * 8;
        short8 b0 = *(const short8*)(bp);
        short8 b1 = *(const short8*)(bp + 512);
        short8 b2 = *(const short8*)(bp + 1024);
        short8 b3 = *(const short8*)(bp + 1536);
        ac0 = __builtin_amdgcn_mfma_f32_16x16x32_bf16(av, b0, ac0, 0, 0, 0);
        ac1 = __builtin_amdgcn_mfma_f32_16x16x32_bf16(av, b1, ac1, 0, 0, 0);
        ac2 = __builtin_amdgcn_mfma_f32_16x16x32_bf16(av, b2, ac2, 0, 0, 0);
        ac3 = __builtin_amdgcn_mfma_f32_16x16x32_bf16(av, b3, ac3, 0, 0, 0);
    }
#pragma unroll
    for (int i = 0; i < 4; ++i) {
        int r = lgrp * 4 + i;
        red[kc][r][lrow]      = ac0[i];
        red[kc][r][16 + lrow] = ac1[i];
        red[kc][r][32 + lrow] = ac2[i];
        red[kc][r][48 + lrow] = ac3[i];
    }
    __syncthreads();

#pragma unroll
    for (int j = 0; j < 2; ++j) {
        int r = 2 * kc + j;
        int grow = rowbase + r;
        if (grow < NROWS) {
            float sv = 0.f;
#pragma unroll
            for (int w = 0; w < 8; ++w) sv += red[w][r][lane];
            float sn2 = wsum(sv * sv);
            float sn = fmaxf(sqrtf(sn2), MINN);
            float th = tanhf(sn);
            float agg = th * sv / sn;          // expmap0; |agg| == th
            if (th > MAXNRM) agg *= MAXNRM / th;
            float lin = liner[(size_t)grow * ODIM + lane];
            zl[r][lane] = agg;
            zl[r][64 + lane] = lin;            // same-wave LDS RAW, no barrier needed
            float d = biasnode[grow];
            const float* w = WN + lane;
#pragma unroll 8
            for (int f = 0; f < 128; ++f) d = fmaf(zl[r][f], w[f * 64], d);
            d = fmaxf(d, 0.0f);
            out_h[(size_t)grow * ODIM + lane] = d * agg + (1.0f - d) * lin;
        }
    }
}

extern "C" void kernel_launch(void* const* d_in, const int* in_sizes, int n_in,
                              void* d_out, int out_size, void* d_ws, size_t ws_size,
                              hipStream_t stream) {
    const float* x   = (const float*)d_in[0];
    const float* adj = (const float*)d_in[1];
    const float* Wd  = (const float*)d_in[2];
    const float* Wm  = (const float*)d_in[3];
    const float* bd  = (const float*)d_in[4];
    const float* bm  = (const float*)d_in[5];
    const float* wn  = (const float*)d_in[6];
    const float* bn  = (const float*)d_in[7];
    float* out = (float*)d_out;

    const int WELEMS = ODIM * INDIM;              // 98944
    unsigned short* WfD = (unsigned short*)d_ws;  // 100352 ushorts each
    unsigned short* WfM = WfD + FRAGSZ;
    unsigned short* xtf = WfM + FRAGSZ;
    float* hbD   = (float*)(xtf + FRAGSZ);        // 3*200704 B -> 4B-aligned
    float* hbM   = hbD + 64;
    float* hb2   = hbM + 64;
    float* liner = hbD + 192;                     // 98944

    int n4 = (NROWS * NROWS) / 4;                 // 597529
    prep_kernel<<<512, 256, 0, stream>>>(Wd, Wm, WfD, WfM, bd, bm, hbD, hbM, hb2,
                                         (const float4*)adj, (float4*)(out + WELEMS), n4);
    liner_fused<<<98, 512, 0, stream>>>(x, WfD, WfM, hbD, hbM, hb2, liner, xtf);
    agg_fused<<<97, 512, 0, stream>>>(adj, xtf, liner, wn, bn, out);
}